// Round 3
// baseline (440.978 us; speedup 1.0000x reference)
//
#include <hip/hip_runtime.h>
#include <hip/hip_bf16.h>
#include <math.h>

#define T_TOK 8192
#define EMB   1024
#define HID   1536
#define NE    8
#define NBINB 64
#define BINTOK (T_TOK / NBINB)

typedef float  floatx4 __attribute__((ext_vector_type(4)));
typedef __bf16 bf16x8  __attribute__((ext_vector_type(8)));

// ---- workspace layout (bytes) ----
#define WS_COUNTS   0
#define WS_OFFSETS  1024
#define WS_FLAGS    2048
#define WS_BHIST    4096
#define WS_TOKMAP   8192        // T*8*4
#define WS_TOKLIST  270336      // NE*T*4
#define WS_YBUF     532480      // ybuf 16384*1024*2; xbf aliases it (dead before gemm2 writes)
#define WS_W1T      34086912    // 25165824
#define WS_W2T      59252736    // 25165824
#define WS_H        84418560    // hbuf 16512 rows * 1536 * 2
#define WS_NEEDED   135143424

__device__ __forceinline__ float eload(const void* p, size_t idx, bool f32) {
  return f32 ? ((const float*)p)[idx] : (float)(((const __bf16*)p)[idx]);
}

// async global->LDS, 16B per lane; LDS dest = wave-uniform base + lane*16
__device__ __forceinline__ void glds16(const void* g, void* l) {
  __builtin_amdgcn_global_load_lds(
      (const __attribute__((address_space(1))) unsigned int*)g,
      (__attribute__((address_space(3))) unsigned int*)l, 16, 0, 0);
}

// ---------------- dtype sniff ----------------
__global__ __launch_bounds__(256)
void sniff_kernel(const void* p0, const void* p1, const void* p2, const void* p3,
                  const void* p4, const void* p5, const void* p6, int* flags) {
  const void* ps[7] = {p0, p1, p2, p3, p4, p5, p6};
  const int nelem[7] = {T_TOK * EMB, EMB * NE, NE, NE * EMB * HID, NE * HID, NE * HID * EMB, NE * EMB};
  int t = blockIdx.x;
  const unsigned* w = (const unsigned*)ps[t];
  int nw = nelem[t] / 2;
  if (nw > 2048) nw = 2048;
  __shared__ int s_pl, s_nz;
  if (threadIdx.x == 0) { s_pl = 0; s_nz = 0; }
  __syncthreads();
  int pl = 0, nz = 0;
  for (int i = threadIdx.x; i < nw; i += 256) {
    unsigned v = w[i];
    if (v == 0) continue;
    nz++;
    unsigned e = (v >> 23) & 0xFF;
    if (e >= 100 && e <= 150) pl++;
  }
  atomicAdd(&s_pl, pl);
  atomicAdd(&s_nz, nz);
  __syncthreads();
  if (threadIdx.x == 0) flags[t] = (2 * s_pl > s_nz) ? 1 : 0;
}

// ---------------- logits + top-k + x->bf16 conversion: one wave per token ----------------
__global__ __launch_bounds__(256)
void logits_kernel(const void* __restrict__ x, const void* __restrict__ Wr,
                   const void* __restrict__ br, const int* __restrict__ kptr,
                   const int* __restrict__ flags, int* __restrict__ topk,
                   __bf16* __restrict__ xbf) {
  const bool xf32  = flags[0] != 0;
  const bool wrf32 = flags[1] != 0;
  const bool brf32 = flags[2] != 0;
  const int wave = threadIdx.x >> 6;
  const int lane = threadIdx.x & 63;
  const int t = blockIdx.x * 4 + wave;

  float xv[16];
  {
    size_t base = (size_t)t * EMB + lane * 16;
    if (xf32) {
      const float* g = (const float*)x + base;
#pragma unroll
      for (int j = 0; j < 16; ++j) xv[j] = g[j];
    } else {
      bf16x8 u = *(const bf16x8*)((const __bf16*)x + base);
      bf16x8 v = *(const bf16x8*)((const __bf16*)x + base + 8);
#pragma unroll
      for (int j = 0; j < 8; ++j) { xv[j] = (float)u[j]; xv[8 + j] = (float)v[j]; }
    }
  }
  // write bf16 copy of x (uniform fast path for gemm1)
  {
    bf16x8 o0, o1;
#pragma unroll
    for (int j = 0; j < 8; ++j) { o0[j] = (__bf16)xv[j]; o1[j] = (__bf16)xv[8 + j]; }
    __bf16* xo = xbf + (size_t)t * EMB + lane * 16;
    *(bf16x8*)xo = o0;
    *(bf16x8*)(xo + 8) = o1;
  }
  float acc[NE];
#pragma unroll
  for (int e = 0; e < NE; ++e) acc[e] = 0.f;
  if (wrf32) {
#pragma unroll
    for (int j = 0; j < 16; ++j) {
      const float* wr = (const float*)Wr + (size_t)(lane * 16 + j) * NE;
#pragma unroll
      for (int e = 0; e < NE; ++e) acc[e] += xv[j] * wr[e];
    }
  } else {
#pragma unroll
    for (int j = 0; j < 16; ++j) {
      bf16x8 wr = *(const bf16x8*)((const __bf16*)Wr + (size_t)(lane * 16 + j) * NE);
#pragma unroll
      for (int e = 0; e < NE; ++e) acc[e] += xv[j] * (float)wr[e];
    }
  }
#pragma unroll
  for (int e = 0; e < NE; ++e) {
#pragma unroll
    for (int off = 32; off > 0; off >>= 1)
      acc[e] += __shfl_xor(acc[e], off, 64);
  }
  if (lane == 0) {
    int k = kptr[0];
    if (k < 1) k = 1; if (k > NE) k = NE;
    float lg[NE];
#pragma unroll
    for (int e = 0; e < NE; ++e) lg[e] = acc[e] + eload(br, e, brf32);
    for (int s = 0; s < k; ++s) {
      int bi = 0; float bv = lg[0];
#pragma unroll
      for (int e = 1; e < NE; ++e) { if (lg[e] > bv) { bv = lg[e]; bi = e; } }
      lg[bi] = -3.0e38f;
      topk[t * 8 + s] = bi;
    }
  }
}

// ---------------- binning: histogram -> scan -> place ----------------
__global__ __launch_bounds__(128)
void bin1_kernel(const int* __restrict__ topk, const int* __restrict__ kptr,
                 int* __restrict__ bhist) {
  __shared__ int lhist[NE];
  if (threadIdx.x < NE) lhist[threadIdx.x] = 0;
  __syncthreads();
  int k = kptr[0];
  if (k < 1) k = 1; if (k > NE) k = NE;
  const int t = blockIdx.x * BINTOK + threadIdx.x;
  for (int s = 0; s < k; ++s) atomicAdd(&lhist[topk[t * 8 + s] & 7], 1);
  __syncthreads();
  if (threadIdx.x < NE) bhist[blockIdx.x * NE + threadIdx.x] = lhist[threadIdx.x];
}

__global__ __launch_bounds__(256)
void scan_kernel(int* __restrict__ bhist, int* __restrict__ counts, int* __restrict__ offsets) {
  __shared__ int sh[NBINB * NE];
  __shared__ int scnt[NE];
  __shared__ int soff[NE + 1];
  const int tid = threadIdx.x;
  for (int i = tid; i < NBINB * NE; i += 256) sh[i] = bhist[i];
  __syncthreads();
  if (tid < NE) {
    int s = 0;
    for (int b = 0; b < NBINB; ++b) s += sh[b * NE + tid];
    scnt[tid] = s;
  }
  __syncthreads();
  if (tid == 0) {
    int s = 0;
    for (int e = 0; e < NE; ++e) { soff[e] = s; s += scnt[e]; }
    soff[NE] = s;
  }
  __syncthreads();
  if (tid < NE) {
    int run = soff[tid];
    for (int b = 0; b < NBINB; ++b) {
      int v = sh[b * NE + tid];
      sh[b * NE + tid] = run;
      run += v;
    }
  }
  __syncthreads();
  for (int i = tid; i < NBINB * NE; i += 256) bhist[i] = sh[i];
  if (tid < NE) counts[tid] = scnt[tid];
  if (tid < NE + 1) offsets[tid] = soff[tid];
}

__global__ __launch_bounds__(128)
void bin2_kernel(const int* __restrict__ bhist, const int* __restrict__ offsets,
                 const int* __restrict__ kptr,
                 int* __restrict__ tok_list, int* __restrict__ tokmap) {
  __shared__ int lbase[NE];
  __shared__ int lcnt[NE];
  if (threadIdx.x < NE) {
    lbase[threadIdx.x] = bhist[blockIdx.x * NE + threadIdx.x];
    lcnt[threadIdx.x] = 0;
  }
  __syncthreads();
  int k = kptr[0];
  if (k < 1) k = 1; if (k > NE) k = NE;
  const int t = blockIdx.x * BINTOK + threadIdx.x;
  for (int s = 0; s < k; ++s) {
    int e = tokmap[t * 8 + s] & 7;
    int pos = atomicAdd(&lcnt[e], 1);
    int grow = lbase[e] + pos;                   // compact global row
    tok_list[e * T_TOK + (grow - offsets[e])] = t;
    tokmap[t * 8 + s] = (e << 16) | grow;
  }
}

// ---------------- per-expert transpose: [K][N] -> [N][K] bf16 ----------------
__global__ __launch_bounds__(256)
void transpose_kernel(const void* __restrict__ in, __bf16* __restrict__ out, int K, int N,
                      const int* __restrict__ flags, int fidx) {
  const bool f32 = flags[fidx] != 0;
  __shared__ __bf16 tile[64][65];
  size_t eoff = (size_t)blockIdx.z * (size_t)K * (size_t)N;
  int n0 = blockIdx.x * 64;
  int k0 = blockIdx.y * 64;
  int tx = threadIdx.x & 63;
  int ty = threadIdx.x >> 6;
#pragma unroll
  for (int i = 0; i < 16; ++i) {
    int r = i * 4 + ty;
    tile[r][tx] = (__bf16)eload(in, eoff + (size_t)(k0 + r) * N + (n0 + tx), f32);
  }
  __syncthreads();
#pragma unroll
  for (int i = 0; i < 16; ++i) {
    int r = i * 4 + ty;
    out[eoff + (size_t)(n0 + r) * K + (k0 + tx)] = tile[tx][r];
  }
}

// =====================================================================
// 128x256 grouped-GEMM core: BK=32, ring-of-3 LDS slots, counted vmcnt.
// 512 threads = 8 waves (2M x 4N), per-wave output 64x64 (acc[4][4]).
// LDS/slot: A[128][32] (8KB) + B[256][32] (16KB) = 24KB; 3 slots = 72KB
// -> 2 blocks/CU (16 waves/CU, 4/SIMD). 16B-chunk XOR swizzle
// chunk^=(row>>1)&3 on pre-swizzled global src + ds_read addrs (rule #21).
// Race-freedom: per-wave s_waitcnt vmcnt(3) BEFORE s_barrier -> slot t
// fully resident at barrier release (in-order vmem retirement, m135).
// STAGE(t+2) post-barrier targets slot (t-1)%3, whose readers finished
// before barrier t. Inter-tile __syncthreads protects slot 0/1 re-stage.
// =====================================================================

#define STAGE3(SL, KO) do {                                              \
    __bf16* _d = lds + (SL) * 12288 + wave * 512;                        \
    glds16(pA0 + (KO), _d);                                              \
    glds16(pB0 + (KO), _d + 4096);                                       \
    glds16(pB1 + (KO), _d + 8192);                                       \
  } while (0)

#define KBODY(SL, DOSTAGE, TT) do {                                      \
    const char* _s = (const char*)lds + (SL) * 24576;                    \
    bf16x8 _af[4], _bf[4];                                               \
    _Pragma("unroll")                                                    \
    for (int _i = 0; _i < 4; ++_i) _af[_i] = *(const bf16x8*)(_s + aOff[_i]); \
    _Pragma("unroll")                                                    \
    for (int _j = 0; _j < 4; ++_j) _bf[_j] = *(const bf16x8*)(_s + bOff[_j]); \
    if (DOSTAGE) { int _sl2 = (SL) == 0 ? 2 : (SL) - 1;                  \
                   STAGE3(_sl2, (size_t)((TT) + 2) * 32); }              \
    __builtin_amdgcn_s_setprio(1);                                       \
    _Pragma("unroll")                                                    \
    for (int _i = 0; _i < 4; ++_i)                                       \
      _Pragma("unroll")                                                  \
      for (int _j = 0; _j < 4; ++_j)                                     \
        acc[_i][_j] = __builtin_amdgcn_mfma_f32_16x16x32_bf16(_af[_i], _bf[_j], acc[_i][_j], 0, 0, 0); \
    __builtin_amdgcn_s_setprio(0);                                       \
  } while (0)

// ---------------- GEMM1: h = gelu(x_gather @ W1[e] + b1[e]) ----------------
__global__ __launch_bounds__(512, 4)
void gemm1_kernel(const __bf16* __restrict__ xbf, const __bf16* __restrict__ w1t,
                  const void* __restrict__ b1, const int* __restrict__ counts,
                  const int* __restrict__ offsets, const int* __restrict__ tok_list,
                  const int* __restrict__ flags, __bf16* __restrict__ hbuf) {
  const int flat = blockIdx.x;
  const int e   = flat & 7;              // expert -> XCD pin
  const int idx = flat >> 3;             // 0..95
  const int g   = idx / 6;               // 0..15 (mT stride group)
  const int nT  = idx % 6;               // 0..5
  const int cnt = counts[e];
  const bool b1f32 = flags[4] != 0;

  __shared__ __align__(16) __bf16 lds[3 * 12288];

  const int wave = threadIdx.x >> 6;
  const int lane = threadIdx.x & 63;
  const int sr = wave * 16 + (lane >> 2);        // staging row 0..127
  const int cg = (lane & 3) ^ ((sr >> 1) & 3);   // swizzled source chunk

  const __bf16* pB0 = w1t + ((size_t)e * HID + nT * 256 + sr) * EMB + cg * 8;
  const __bf16* pB1 = w1t + ((size_t)e * HID + nT * 256 + 128 + sr) * EMB + cg * 8;

  const int wm = (wave >> 2) * 64;
  const int wn = (wave & 3) * 64;
  const int fr = lane & 15;
  const int fc = lane >> 4;                      // 0..3 (k-chunk)
  int aOff[4], bOff[4];
#pragma unroll
  for (int i = 0; i < 4; ++i) { int R = wm + i * 16 + fr; aOff[i] = R * 64 + ((fc ^ ((R >> 1) & 3)) << 4); }
#pragma unroll
  for (int j = 0; j < 4; ++j) { int R = wn + j * 16 + fr; bOff[j] = 8192 + R * 64 + ((fc ^ ((R >> 1) & 3)) << 4); }

  const int colBase = nT * 256 + wn + fr;
  float bv[4];
#pragma unroll
  for (int j = 0; j < 4; ++j) bv[j] = eload(b1, (size_t)e * HID + colBase + j * 16, b1f32);

  for (int mT = g; mT * 128 < cnt; mT += 16) {
    const int tokA = tok_list[e * T_TOK + mT * 128 + sr];  // pad entries = 0
    const __bf16* pA0 = xbf + (size_t)tokA * EMB + cg * 8;

    floatx4 acc[4][4];
#pragma unroll
    for (int i = 0; i < 4; ++i)
#pragma unroll
      for (int j = 0; j < 4; ++j) acc[i][j] = (floatx4){0.f, 0.f, 0.f, 0.f};

    __syncthreads();                              // protect slots across tiles
    STAGE3(0, 0); STAGE3(1, 32);
    int sl = 0;
    for (int t = 0; t < 31; ++t) {
      asm volatile("s_waitcnt vmcnt(3)" ::: "memory");
      __builtin_amdgcn_s_barrier();
      KBODY(sl, (t + 2 < 32), t);
      sl = (sl + 1 == 3) ? 0 : sl + 1;
    }
    asm volatile("s_waitcnt vmcnt(0)" ::: "memory");
    __builtin_amdgcn_s_barrier();
    KBODY(sl, 0, 0);

    const int hBase = offsets[e] + mT * 128;
#pragma unroll
    for (int i = 0; i < 4; ++i) {
      const int rowLoc = wm + i * 16 + fc * 4;
#pragma unroll
      for (int r = 0; r < 4; ++r) {
        const int row = rowLoc + r;
        if (mT * 128 + row < cnt) {
          __bf16* hp = hbuf + (size_t)(hBase + row) * HID + colBase;
#pragma unroll
          for (int j = 0; j < 4; ++j) {
            float v = acc[i][j][r] + bv[j];
            float gl = 0.5f * v * (1.0f + erff(v * 0.70710678118654752f));
            hp[j * 16] = (__bf16)gl;
          }
        }
      }
    }
  }
}

// ---------------- GEMM2: ybuf[row] = h @ W2[e] + b2[e] ----------------
__global__ __launch_bounds__(512, 4)
void gemm2_kernel(const __bf16* __restrict__ hbuf, const __bf16* __restrict__ w2t,
                  const void* __restrict__ b2, const int* __restrict__ counts,
                  const int* __restrict__ offsets, const int* __restrict__ flags,
                  __bf16* __restrict__ ybuf) {
  const int flat = blockIdx.x;
  const int e   = flat & 7;
  const int idx = flat >> 3;             // 0..63
  const int g   = idx >> 2;              // 0..15
  const int nT  = idx & 3;               // 0..3
  const int cnt = counts[e];
  const bool b2f32 = flags[6] != 0;

  __shared__ __align__(16) __bf16 lds[3 * 12288];

  const int wave = threadIdx.x >> 6;
  const int lane = threadIdx.x & 63;
  const int sr = wave * 16 + (lane >> 2);
  const int cg = (lane & 3) ^ ((sr >> 1) & 3);

  const __bf16* pB0 = w2t + ((size_t)e * EMB + nT * 256 + sr) * HID + cg * 8;
  const __bf16* pB1 = w2t + ((size_t)e * EMB + nT * 256 + 128 + sr) * HID + cg * 8;

  const int wm = (wave >> 2) * 64;
  const int wn = (wave & 3) * 64;
  const int fr = lane & 15;
  const int fc = lane >> 4;
  int aOff[4], bOff[4];
#pragma unroll
  for (int i = 0; i < 4; ++i) { int R = wm + i * 16 + fr; aOff[i] = R * 64 + ((fc ^ ((R >> 1) & 3)) << 4); }
#pragma unroll
  for (int j = 0; j < 4; ++j) { int R = wn + j * 16 + fr; bOff[j] = 8192 + R * 64 + ((fc ^ ((R >> 1) & 3)) << 4); }

  const int colBase = nT * 256 + wn + fr;
  float bv[4];
#pragma unroll
  for (int j = 0; j < 4; ++j) bv[j] = eload(b2, (size_t)e * EMB + colBase + j * 16, b2f32);

  const int lastRow = offsets[NE] - 1;

  for (int mT = g; mT * 128 < cnt; mT += 16) {
    const int rowBase = offsets[e] + mT * 128;
    const int rA = min(rowBase + sr, lastRow);   // clamp: tile may overhang
    const __bf16* pA0 = hbuf + (size_t)rA * HID + cg * 8;

    floatx4 acc[4][4];
#pragma unroll
    for (int i = 0; i < 4; ++i)
#pragma unroll
      for (int j = 0; j < 4; ++j) acc[i][j] = (floatx4){0.f, 0.f, 0.f, 0.f};

    __syncthreads();
    STAGE3(0, 0); STAGE3(1, 32);
    int sl = 0;
    for (int t = 0; t < 47; ++t) {
      asm volatile("s_waitcnt vmcnt(3)" ::: "memory");
      __builtin_amdgcn_s_barrier();
      KBODY(sl, (t + 2 < 48), t);
      sl = (sl + 1 == 3) ? 0 : sl + 1;
    }
    asm volatile("s_waitcnt vmcnt(0)" ::: "memory");
    __builtin_amdgcn_s_barrier();
    KBODY(sl, 0, 0);

#pragma unroll
    for (int i = 0; i < 4; ++i) {
      const int rowLoc = wm + i * 16 + fc * 4;
#pragma unroll
      for (int r = 0; r < 4; ++r) {
        const int row = rowLoc + r;
        if (mT * 128 + row < cnt) {
          __bf16* yp = ybuf + (size_t)(rowBase + row) * EMB + colBase;
#pragma unroll
          for (int j = 0; j < 4; ++j)
            yp[j * 16] = (__bf16)(acc[i][j][r] + bv[j]);
        }
      }
    }
  }
}

// ---------------- combine: out[t] = (sum_s ybuf[row(t,s)]) / k ----------------
__global__ __launch_bounds__(256)
void combine_kernel(const __bf16* __restrict__ ybuf, const int* __restrict__ tokmap,
                    const int* __restrict__ kptr, const int* __restrict__ flags,
                    void* __restrict__ out) {
  const bool f32 = flags[0] != 0;
  const int wave = threadIdx.x >> 6;
  const int lane = threadIdx.x & 63;
  const int t = blockIdx.x * 4 + wave;
  int k = kptr[0];
  if (k < 1) k = 1; if (k > NE) k = NE;
  const float invk = 1.0f / (float)k;
  int rows[NE];
  for (int s = 0; s < k; ++s) rows[s] = tokmap[t * 8 + s] & 0xFFFF;
#pragma unroll
  for (int c = 0; c < 2; ++c) {
    const int i = c * 512 + lane * 8;
    float a[8];
#pragma unroll
    for (int j = 0; j < 8; ++j) a[j] = 0.f;
    for (int s = 0; s < k; ++s) {
      bf16x8 y = *(const bf16x8*)(ybuf + (size_t)rows[s] * EMB + i);
#pragma unroll
      for (int j = 0; j < 8; ++j) a[j] += (float)y[j];
    }
    if (f32) {
      float* op = (float*)out + (size_t)t * EMB + i;
      float4 u = {a[0] * invk, a[1] * invk, a[2] * invk, a[3] * invk};
      float4 v = {a[4] * invk, a[5] * invk, a[6] * invk, a[7] * invk};
      *(float4*)op = u;
      *(float4*)(op + 4) = v;
    } else {
      bf16x8 o;
#pragma unroll
      for (int j = 0; j < 8; ++j) o[j] = (__bf16)(a[j] * invk);
      *(bf16x8*)((__bf16*)out + (size_t)t * EMB + i) = o;
    }
  }
}

extern "C" void kernel_launch(void* const* d_in, const int* in_sizes, int n_in,
                              void* d_out, int out_size, void* d_ws, size_t ws_size,
                              hipStream_t stream) {
  (void)in_sizes; (void)n_in; (void)out_size;
  if (ws_size < (size_t)WS_NEEDED) return;

  const void* x  = d_in[0];
  const void* Wr = d_in[1];
  const void* br = d_in[2];
  const void* W1 = d_in[3];
  const void* b1 = d_in[4];
  const void* W2 = d_in[5];
  const void* b2 = d_in[6];
  const int* kptr = (const int*)d_in[7];

  char* ws = (char*)d_ws;
  int*    counts   = (int*)(ws + WS_COUNTS);
  int*    offsets  = (int*)(ws + WS_OFFSETS);
  int*    flags    = (int*)(ws + WS_FLAGS);
  int*    bhist    = (int*)(ws + WS_BHIST);
  int*    tokmap   = (int*)(ws + WS_TOKMAP);
  int*    tok_list = (int*)(ws + WS_TOKLIST);
  __bf16* ybuf     = (__bf16*)(ws + WS_YBUF);
  __bf16* xbf      = (__bf16*)(ws + WS_YBUF);   // aliases ybuf; dead before gemm2 writes
  __bf16* w1t      = (__bf16*)(ws + WS_W1T);
  __bf16* w2t      = (__bf16*)(ws + WS_W2T);
  __bf16* hbuf     = (__bf16*)(ws + WS_H);

  hipMemsetAsync(ws, 0, WS_YBUF, stream);

  sniff_kernel<<<dim3(7), 256, 0, stream>>>(x, Wr, br, W1, b1, W2, b2, flags);

  transpose_kernel<<<dim3(HID / 64, EMB / 64, NE), 256, 0, stream>>>(W1, w1t, EMB, HID, flags, 3);
  transpose_kernel<<<dim3(EMB / 64, HID / 64, NE), 256, 0, stream>>>(W2, w2t, HID, EMB, flags, 5);

  logits_kernel<<<dim3(T_TOK / 4), 256, 0, stream>>>(x, Wr, br, kptr, flags, tokmap, xbf);
  bin1_kernel<<<dim3(NBINB), 128, 0, stream>>>(tokmap, kptr, bhist);
  scan_kernel<<<dim3(1), 256, 0, stream>>>(bhist, counts, offsets);
  bin2_kernel<<<dim3(NBINB), 128, 0, stream>>>(bhist, offsets, kptr, tok_list, tokmap);

  gemm1_kernel<<<dim3(8 * 16 * 6), 512, 0, stream>>>(
      xbf, w1t, b1, counts, offsets, tok_list, flags, hbuf);
  gemm2_kernel<<<dim3(8 * 16 * 4), 512, 0, stream>>>(
      hbuf, w2t, b2, counts, offsets, flags, ybuf);

  combine_kernel<<<dim3(T_TOK / 4), 256, 0, stream>>>(ybuf, tokmap, kptr, flags, d_out);
}

// Round 7
// 401.090 us; speedup vs baseline: 1.0994x; 1.0994x over previous
//
#include <hip/hip_runtime.h>
#include <hip/hip_bf16.h>
#include <math.h>

#define T_TOK 8192
#define EMB   1024
#define HID   1536
#define NE    8
#define NBINB 64
#define BINTOK (T_TOK / NBINB)

typedef float  floatx4 __attribute__((ext_vector_type(4)));
typedef __bf16 bf16x8  __attribute__((ext_vector_type(8)));

// ---- workspace layout (bytes) ----
#define WS_COUNTS   0
#define WS_OFFSETS  1024
#define WS_FLAGS    2048
#define WS_BHIST    4096
#define WS_TOKMAP   8192        // T*8*4
#define WS_TOKLIST  270336      // NE*T*4
#define WS_YBUF     532480      // ybuf 16384*1024*2; xbf aliases it (dead before gemm2 writes)
#define WS_W1T      34086912    // 25165824
#define WS_W2T      59252736    // 25165824
#define WS_H        84418560    // hbuf 16512 rows * 1536 * 2 (128-row pad for tail tiles)
#define WS_NEEDED   135143424

__device__ __forceinline__ float eload(const void* p, size_t idx, bool f32) {
  return f32 ? ((const float*)p)[idx] : (float)(((const __bf16*)p)[idx]);
}

// async global->LDS, 16B per lane; LDS dest = wave-uniform base + lane*16
__device__ __forceinline__ void glds16(const void* g, void* l) {
  __builtin_amdgcn_global_load_lds(
      (const __attribute__((address_space(1))) unsigned int*)g,
      (__attribute__((address_space(3))) unsigned int*)l, 16, 0, 0);
}

// ---------------- dtype sniff ----------------
__global__ __launch_bounds__(256)
void sniff_kernel(const void* p0, const void* p1, const void* p2, const void* p3,
                  const void* p4, const void* p5, const void* p6, int* flags) {
  const void* ps[7] = {p0, p1, p2, p3, p4, p5, p6};
  const int nelem[7] = {T_TOK * EMB, EMB * NE, NE, NE * EMB * HID, NE * HID, NE * HID * EMB, NE * EMB};
  int t = blockIdx.x;
  const unsigned* w = (const unsigned*)ps[t];
  int nw = nelem[t] / 2;
  if (nw > 2048) nw = 2048;
  __shared__ int s_pl, s_nz;
  if (threadIdx.x == 0) { s_pl = 0; s_nz = 0; }
  __syncthreads();
  int pl = 0, nz = 0;
  for (int i = threadIdx.x; i < nw; i += 256) {
    unsigned v = w[i];
    if (v == 0) continue;
    nz++;
    unsigned e = (v >> 23) & 0xFF;
    if (e >= 100 && e <= 150) pl++;
  }
  atomicAdd(&s_pl, pl);
  atomicAdd(&s_nz, nz);
  __syncthreads();
  if (threadIdx.x == 0) flags[t] = (2 * s_pl > s_nz) ? 1 : 0;
}

// ---------------- logits + top-k + x->bf16 conversion: one wave per token ----------------
__global__ __launch_bounds__(256)
void logits_kernel(const void* __restrict__ x, const void* __restrict__ Wr,
                   const void* __restrict__ br, const int* __restrict__ kptr,
                   const int* __restrict__ flags, int* __restrict__ topk,
                   __bf16* __restrict__ xbf) {
  const bool xf32  = flags[0] != 0;
  const bool wrf32 = flags[1] != 0;
  const bool brf32 = flags[2] != 0;
  const int wave = threadIdx.x >> 6;
  const int lane = threadIdx.x & 63;
  const int t = blockIdx.x * 4 + wave;

  float xv[16];
  {
    size_t base = (size_t)t * EMB + lane * 16;
    if (xf32) {
      const float* g = (const float*)x + base;
#pragma unroll
      for (int j = 0; j < 16; ++j) xv[j] = g[j];
    } else {
      bf16x8 u = *(const bf16x8*)((const __bf16*)x + base);
      bf16x8 v = *(const bf16x8*)((const __bf16*)x + base + 8);
#pragma unroll
      for (int j = 0; j < 8; ++j) { xv[j] = (float)u[j]; xv[8 + j] = (float)v[j]; }
    }
  }
  // write bf16 copy of x (uniform fast path for gemm1)
  {
    bf16x8 o0, o1;
#pragma unroll
    for (int j = 0; j < 8; ++j) { o0[j] = (__bf16)xv[j]; o1[j] = (__bf16)xv[8 + j]; }
    __bf16* xo = xbf + (size_t)t * EMB + lane * 16;
    *(bf16x8*)xo = o0;
    *(bf16x8*)(xo + 8) = o1;
  }
  float acc[NE];
#pragma unroll
  for (int e = 0; e < NE; ++e) acc[e] = 0.f;
  if (wrf32) {
#pragma unroll
    for (int j = 0; j < 16; ++j) {
      const float* wr = (const float*)Wr + (size_t)(lane * 16 + j) * NE;
#pragma unroll
      for (int e = 0; e < NE; ++e) acc[e] += xv[j] * wr[e];
    }
  } else {
#pragma unroll
    for (int j = 0; j < 16; ++j) {
      bf16x8 wr = *(const bf16x8*)((const __bf16*)Wr + (size_t)(lane * 16 + j) * NE);
#pragma unroll
      for (int e = 0; e < NE; ++e) acc[e] += xv[j] * (float)wr[e];
    }
  }
#pragma unroll
  for (int e = 0; e < NE; ++e) {
#pragma unroll
    for (int off = 32; off > 0; off >>= 1)
      acc[e] += __shfl_xor(acc[e], off, 64);
  }
  if (lane == 0) {
    int k = kptr[0];
    if (k < 1) k = 1; if (k > NE) k = NE;
    float lg[NE];
#pragma unroll
    for (int e = 0; e < NE; ++e) lg[e] = acc[e] + eload(br, e, brf32);
    for (int s = 0; s < k; ++s) {
      int bi = 0; float bv = lg[0];
#pragma unroll
      for (int e = 1; e < NE; ++e) { if (lg[e] > bv) { bv = lg[e]; bi = e; } }
      lg[bi] = -3.0e38f;
      topk[t * 8 + s] = bi;
    }
  }
}

// ---------------- binning: histogram -> scan -> place ----------------
__global__ __launch_bounds__(128)
void bin1_kernel(const int* __restrict__ topk, const int* __restrict__ kptr,
                 int* __restrict__ bhist) {
  __shared__ int lhist[NE];
  if (threadIdx.x < NE) lhist[threadIdx.x] = 0;
  __syncthreads();
  int k = kptr[0];
  if (k < 1) k = 1; if (k > NE) k = NE;
  const int t = blockIdx.x * BINTOK + threadIdx.x;
  for (int s = 0; s < k; ++s) atomicAdd(&lhist[topk[t * 8 + s] & 7], 1);
  __syncthreads();
  if (threadIdx.x < NE) bhist[blockIdx.x * NE + threadIdx.x] = lhist[threadIdx.x];
}

__global__ __launch_bounds__(256)
void scan_kernel(int* __restrict__ bhist, int* __restrict__ counts, int* __restrict__ offsets) {
  __shared__ int sh[NBINB * NE];
  __shared__ int scnt[NE];
  __shared__ int soff[NE + 1];
  const int tid = threadIdx.x;
  for (int i = tid; i < NBINB * NE; i += 256) sh[i] = bhist[i];
  __syncthreads();
  if (tid < NE) {
    int s = 0;
    for (int b = 0; b < NBINB; ++b) s += sh[b * NE + tid];
    scnt[tid] = s;
  }
  __syncthreads();
  if (tid == 0) {
    int s = 0;
    for (int e = 0; e < NE; ++e) { soff[e] = s; s += scnt[e]; }
    soff[NE] = s;
  }
  __syncthreads();
  if (tid < NE) {
    int run = soff[tid];
    for (int b = 0; b < NBINB; ++b) {
      int v = sh[b * NE + tid];
      sh[b * NE + tid] = run;
      run += v;
    }
  }
  __syncthreads();
  for (int i = tid; i < NBINB * NE; i += 256) bhist[i] = sh[i];
  if (tid < NE) counts[tid] = scnt[tid];
  if (tid < NE + 1) offsets[tid] = soff[tid];
}

__global__ __launch_bounds__(128)
void bin2_kernel(const int* __restrict__ bhist, const int* __restrict__ offsets,
                 const int* __restrict__ kptr,
                 int* __restrict__ tok_list, int* __restrict__ tokmap) {
  __shared__ int lbase[NE];
  __shared__ int lcnt[NE];
  if (threadIdx.x < NE) {
    lbase[threadIdx.x] = bhist[blockIdx.x * NE + threadIdx.x];
    lcnt[threadIdx.x] = 0;
  }
  __syncthreads();
  int k = kptr[0];
  if (k < 1) k = 1; if (k > NE) k = NE;
  const int t = blockIdx.x * BINTOK + threadIdx.x;
  for (int s = 0; s < k; ++s) {
    int e = tokmap[t * 8 + s] & 7;
    int pos = atomicAdd(&lcnt[e], 1);
    int grow = lbase[e] + pos;                   // compact global row
    tok_list[e * T_TOK + (grow - offsets[e])] = t;
    tokmap[t * 8 + s] = (e << 16) | grow;
  }
}

// ---------------- fused per-expert transposes: W1 [E][H]->[H][E], W2 [H][E]->[E][H] ----------------
__global__ __launch_bounds__(256)
void transpose2_kernel(const void* __restrict__ W1, const void* __restrict__ W2,
                       __bf16* __restrict__ w1t, __bf16* __restrict__ w2t,
                       const int* __restrict__ flags) {
  const int z = blockIdx.z;             // 0..7 -> W1 expert z ; 8..15 -> W2 expert z-8
  const void* in; __bf16* out; int K, N; bool f32;
  if (z < 8) { in = W1; out = w1t; K = EMB; N = HID; f32 = flags[3] != 0; }
  else       { in = W2; out = w2t; K = HID; N = EMB; f32 = flags[5] != 0; }
  if ((int)blockIdx.x * 64 >= N || (int)blockIdx.y * 64 >= K) return;
  __shared__ __bf16 tile[64][65];
  size_t eoff = (size_t)(z & 7) * (size_t)K * (size_t)N;
  int n0 = blockIdx.x * 64;
  int k0 = blockIdx.y * 64;
  int tx = threadIdx.x & 63;
  int ty = threadIdx.x >> 6;
#pragma unroll
  for (int i = 0; i < 16; ++i) {
    int r = i * 4 + ty;
    tile[r][tx] = (__bf16)eload(in, eoff + (size_t)(k0 + r) * N + (n0 + tx), f32);
  }
  __syncthreads();
#pragma unroll
  for (int i = 0; i < 16; ++i) {
    int r = i * 4 + ty;
    out[eoff + (size_t)(n0 + r) * K + (k0 + tx)] = tile[tx][r];
  }
}

// =====================================================================
// m97-structure grouped GEMM: 128x128 tile, BK=32, 256 threads = 4 waves
// (2Mx2N, per-wave 64x64, acc[4][4]). Single 16KB LDS buffer, 2 barriers
// per K-step (compiler inserts vmcnt(0)/lgkmcnt(0) drains). TLP does the
// latency hiding: 16KB LDS + ~64-110 VGPR -> 4-8 blocks/CU (m114).
// 16B-chunk XOR swizzle chunk^=(row>>1)&3 on pre-swizzled global src +
// ds_read addrs (rule #21; proven 0-conflict in rounds 2-3).
// Second-half staging base: row 64 of a [128][32] bf16 tile = ELEMENT
// 2048 (64*32), byte 4096. Round-4/5/6 bug: used +4096 elements (row
// 128) -> A-rows 64..127 overwrote Bs, B-rows 64..127 wrote past the
// 16KB LDS block -> NaN + container crash. Fixed to +2048.
// M-tiles: strided persistent loop (mT = g, g+16, ...) covers any cnt.
// =====================================================================

// ---------------- GEMM1: h = gelu(x_gather @ W1[e] + b1[e]) ----------------
__global__ __launch_bounds__(256, 4)
void gemm1_kernel(const __bf16* __restrict__ xbf, const __bf16* __restrict__ w1t,
                  const void* __restrict__ b1, const int* __restrict__ counts,
                  const int* __restrict__ offsets, const int* __restrict__ tok_list,
                  const int* __restrict__ flags, __bf16* __restrict__ hbuf) {
  const int flat = blockIdx.x;
  const int e   = flat & 7;              // expert -> XCD pin
  const int idx = flat >> 3;             // 0..191
  const int g   = idx / 12;              // 0..15 (mT stride group)
  const int nT  = idx % 12;              // 0..11
  const int cnt = counts[e];
  const bool b1f32 = flags[4] != 0;

  __shared__ __align__(16) __bf16 As[128 * 32];
  __shared__ __align__(16) __bf16 Bs[128 * 32];

  const int wave = threadIdx.x >> 6;
  const int lane = threadIdx.x & 63;
  const int sr = lane >> 2;              // 0..15
  const int r0 = wave * 16 + sr;         // rows 0..63
  const int r1 = 64 + wave * 16 + sr;    // rows 64..127
  const int cg = (lane & 3) ^ ((r0 >> 1) & 3);   // swizzled src chunk (same for r1: +64 rows)

  const __bf16* pB0base = w1t + ((size_t)e * HID + nT * 128 + r0) * EMB + cg * 8;
  const __bf16* pB1base = w1t + ((size_t)e * HID + nT * 128 + r1) * EMB + cg * 8;

  __bf16* dA0 = As + wave * 512;         // rows 0..63: elem wave*512
  __bf16* dA1 = As + 2048 + wave * 512;  // rows 64..127: elem 2048 + wave*512 (64*32=2048)
  __bf16* dB0 = Bs + wave * 512;
  __bf16* dB1 = Bs + 2048 + wave * 512;

  const int wm = (wave & 1) * 64;
  const int wn = (wave >> 1) * 64;
  const int fr = lane & 15;
  const int fc = lane >> 4;              // 0..3 (16B k-chunk)
  int aOff[4], bOff[4];
#pragma unroll
  for (int i = 0; i < 4; ++i) { int R = wm + i * 16 + fr; aOff[i] = R * 64 + ((fc ^ ((R >> 1) & 3)) << 4); }
#pragma unroll
  for (int j = 0; j < 4; ++j) { int R = wn + j * 16 + fr; bOff[j] = R * 64 + ((fc ^ ((R >> 1) & 3)) << 4); }

  const int colBase = nT * 128 + wn + fr;
  float bv[4];
#pragma unroll
  for (int j = 0; j < 4; ++j) bv[j] = eload(b1, (size_t)e * HID + colBase + j * 16, b1f32);

  for (int mT = g; mT * 128 < cnt; mT += 16) {
    const int tokA0 = tok_list[e * T_TOK + mT * 128 + r0];  // pad entries = 0
    const int tokA1 = tok_list[e * T_TOK + mT * 128 + r1];
    const __bf16* pA0 = xbf + (size_t)tokA0 * EMB + cg * 8;
    const __bf16* pA1 = xbf + (size_t)tokA1 * EMB + cg * 8;
    const __bf16* pB0 = pB0base;
    const __bf16* pB1 = pB1base;

    floatx4 acc[4][4];
#pragma unroll
    for (int i = 0; i < 4; ++i)
#pragma unroll
      for (int j = 0; j < 4; ++j) acc[i][j] = (floatx4){0.f, 0.f, 0.f, 0.f};

    for (int kb = 0; kb < EMB / 32; ++kb) {
      __syncthreads();                   // previous step's (and tile's) readers done
      glds16(pA0, dA0); glds16(pA1, dA1);
      glds16(pB0, dB0); glds16(pB1, dB1);
      pA0 += 32; pA1 += 32; pB0 += 32; pB1 += 32;
      __syncthreads();                   // vmcnt(0) drain -> LDS resident
      bf16x8 af[4], bfr[4];
#pragma unroll
      for (int i = 0; i < 4; ++i) af[i]  = *(const bf16x8*)((const char*)As + aOff[i]);
#pragma unroll
      for (int j = 0; j < 4; ++j) bfr[j] = *(const bf16x8*)((const char*)Bs + bOff[j]);
#pragma unroll
      for (int i = 0; i < 4; ++i)
#pragma unroll
        for (int j = 0; j < 4; ++j)
          acc[i][j] = __builtin_amdgcn_mfma_f32_16x16x32_bf16(af[i], bfr[j], acc[i][j], 0, 0, 0);
    }

    const int hBase = offsets[e] + mT * 128;
#pragma unroll
    for (int i = 0; i < 4; ++i) {
      const int rowLoc = wm + i * 16 + fc * 4;
#pragma unroll
      for (int r = 0; r < 4; ++r) {
        const int row = rowLoc + r;
        if (mT * 128 + row < cnt) {
          __bf16* hp = hbuf + (size_t)(hBase + row) * HID + colBase;
#pragma unroll
          for (int j = 0; j < 4; ++j) {
            float v = acc[i][j][r] + bv[j];
            float gl = 0.5f * v * (1.0f + erff(v * 0.70710678118654752f));
            hp[j * 16] = (__bf16)gl;
          }
        }
      }
    }
  }
}

// ---------------- GEMM2: ybuf[row] = h @ W2[e] + b2[e] ----------------
__global__ __launch_bounds__(256, 4)
void gemm2_kernel(const __bf16* __restrict__ hbuf, const __bf16* __restrict__ w2t,
                  const void* __restrict__ b2, const int* __restrict__ counts,
                  const int* __restrict__ offsets, const int* __restrict__ flags,
                  __bf16* __restrict__ ybuf) {
  const int flat = blockIdx.x;
  const int e   = flat & 7;
  const int idx = flat >> 3;             // 0..127
  const int g   = idx >> 3;              // 0..15
  const int nT  = idx & 7;               // 0..7
  const int cnt = counts[e];
  const bool b2f32 = flags[6] != 0;

  __shared__ __align__(16) __bf16 As[128 * 32];
  __shared__ __align__(16) __bf16 Bs[128 * 32];

  const int wave = threadIdx.x >> 6;
  const int lane = threadIdx.x & 63;
  const int sr = lane >> 2;
  const int r0 = wave * 16 + sr;
  const int r1 = 64 + wave * 16 + sr;
  const int cg = (lane & 3) ^ ((r0 >> 1) & 3);

  const __bf16* pB0base = w2t + ((size_t)e * EMB + nT * 128 + r0) * HID + cg * 8;
  const __bf16* pB1base = w2t + ((size_t)e * EMB + nT * 128 + r1) * HID + cg * 8;

  __bf16* dA0 = As + wave * 512;
  __bf16* dA1 = As + 2048 + wave * 512;  // row 64 = elem 2048 (fix)
  __bf16* dB0 = Bs + wave * 512;
  __bf16* dB1 = Bs + 2048 + wave * 512;

  const int wm = (wave & 1) * 64;
  const int wn = (wave >> 1) * 64;
  const int fr = lane & 15;
  const int fc = lane >> 4;
  int aOff[4], bOff[4];
#pragma unroll
  for (int i = 0; i < 4; ++i) { int R = wm + i * 16 + fr; aOff[i] = R * 64 + ((fc ^ ((R >> 1) & 3)) << 4); }
#pragma unroll
  for (int j = 0; j < 4; ++j) { int R = wn + j * 16 + fr; bOff[j] = R * 64 + ((fc ^ ((R >> 1) & 3)) << 4); }

  const int colBase = nT * 128 + wn + fr;
  float bv[4];
#pragma unroll
  for (int j = 0; j < 4; ++j) bv[j] = eload(b2, (size_t)e * EMB + colBase + j * 16, b2f32);

  for (int mT = g; mT * 128 < cnt; mT += 16) {
    const int rowBase = offsets[e] + mT * 128;
    // overhang rows read next expert's rows / 128-row hbuf pad (<16512): discarded per-row below
    const __bf16* pA0 = hbuf + (size_t)(rowBase + r0) * HID + cg * 8;
    const __bf16* pA1 = hbuf + (size_t)(rowBase + r1) * HID + cg * 8;
    const __bf16* pB0 = pB0base;
    const __bf16* pB1 = pB1base;

    floatx4 acc[4][4];
#pragma unroll
    for (int i = 0; i < 4; ++i)
#pragma unroll
      for (int j = 0; j < 4; ++j) acc[i][j] = (floatx4){0.f, 0.f, 0.f, 0.f};

    for (int kb = 0; kb < HID / 32; ++kb) {
      __syncthreads();
      glds16(pA0, dA0); glds16(pA1, dA1);
      glds16(pB0, dB0); glds16(pB1, dB1);
      pA0 += 32; pA1 += 32; pB0 += 32; pB1 += 32;
      __syncthreads();
      bf16x8 af[4], bfr[4];
#pragma unroll
      for (int i = 0; i < 4; ++i) af[i]  = *(const bf16x8*)((const char*)As + aOff[i]);
#pragma unroll
      for (int j = 0; j < 4; ++j) bfr[j] = *(const bf16x8*)((const char*)Bs + bOff[j]);
#pragma unroll
      for (int i = 0; i < 4; ++i)
#pragma unroll
        for (int j = 0; j < 4; ++j)
          acc[i][j] = __builtin_amdgcn_mfma_f32_16x16x32_bf16(af[i], bfr[j], acc[i][j], 0, 0, 0);
    }

#pragma unroll
    for (int i = 0; i < 4; ++i) {
      const int rowLoc = wm + i * 16 + fc * 4;
#pragma unroll
      for (int r = 0; r < 4; ++r) {
        const int row = rowLoc + r;
        if (mT * 128 + row < cnt) {
          __bf16* yp = ybuf + (size_t)(rowBase + row) * EMB + colBase;
#pragma unroll
          for (int j = 0; j < 4; ++j)
            yp[j * 16] = (__bf16)(acc[i][j][r] + bv[j]);
        }
      }
    }
  }
}

// ---------------- combine: out[t] = (sum_s ybuf[row(t,s)]) / k ----------------
__global__ __launch_bounds__(256)
void combine_kernel(const __bf16* __restrict__ ybuf, const int* __restrict__ tokmap,
                    const int* __restrict__ kptr, const int* __restrict__ flags,
                    void* __restrict__ out) {
  const bool f32 = flags[0] != 0;
  const int wave = threadIdx.x >> 6;
  const int lane = threadIdx.x & 63;
  const int t = blockIdx.x * 4 + wave;
  int k = kptr[0];
  if (k < 1) k = 1; if (k > NE) k = NE;
  const float invk = 1.0f / (float)k;
  int rows[NE];
  for (int s = 0; s < k; ++s) rows[s] = tokmap[t * 8 + s] & 0xFFFF;
#pragma unroll
  for (int c = 0; c < 2; ++c) {
    const int i = c * 512 + lane * 8;
    float a[8];
#pragma unroll
    for (int j = 0; j < 8; ++j) a[j] = 0.f;
    for (int s = 0; s < k; ++s) {
      bf16x8 y = *(const bf16x8*)(ybuf + (size_t)rows[s] * EMB + i);
#pragma unroll
      for (int j = 0; j < 8; ++j) a[j] += (float)y[j];
    }
    if (f32) {
      float* op = (float*)out + (size_t)t * EMB + i;
      float4 u = {a[0] * invk, a[1] * invk, a[2] * invk, a[3] * invk};
      float4 v = {a[4] * invk, a[5] * invk, a[6] * invk, a[7] * invk};
      *(float4*)op = u;
      *(float4*)(op + 4) = v;
    } else {
      bf16x8 o;
#pragma unroll
      for (int j = 0; j < 8; ++j) o[j] = (__bf16)(a[j] * invk);
      *(bf16x8*)((__bf16*)out + (size_t)t * EMB + i) = o;
    }
  }
}

extern "C" void kernel_launch(void* const* d_in, const int* in_sizes, int n_in,
                              void* d_out, int out_size, void* d_ws, size_t ws_size,
                              hipStream_t stream) {
  (void)in_sizes; (void)n_in; (void)out_size;
  if (ws_size < (size_t)WS_NEEDED) return;

  const void* x  = d_in[0];
  const void* Wr = d_in[1];
  const void* br = d_in[2];
  const void* W1 = d_in[3];
  const void* b1 = d_in[4];
  const void* W2 = d_in[5];
  const void* b2 = d_in[6];
  const int* kptr = (const int*)d_in[7];

  char* ws = (char*)d_ws;
  int*    counts   = (int*)(ws + WS_COUNTS);
  int*    offsets  = (int*)(ws + WS_OFFSETS);
  int*    flags    = (int*)(ws + WS_FLAGS);
  int*    bhist    = (int*)(ws + WS_BHIST);
  int*    tokmap   = (int*)(ws + WS_TOKMAP);
  int*    tok_list = (int*)(ws + WS_TOKLIST);
  __bf16* ybuf     = (__bf16*)(ws + WS_YBUF);
  __bf16* xbf      = (__bf16*)(ws + WS_YBUF);   // aliases ybuf; dead before gemm2 writes
  __bf16* w1t      = (__bf16*)(ws + WS_W1T);
  __bf16* w2t      = (__bf16*)(ws + WS_W2T);
  __bf16* hbuf     = (__bf16*)(ws + WS_H);

  // only the tok_list pad must be deterministic (gemm1 tail tiles read it)
  hipMemsetAsync(ws + WS_TOKLIST, 0, NE * T_TOK * 4, stream);

  sniff_kernel<<<dim3(7), 256, 0, stream>>>(x, Wr, br, W1, b1, W2, b2, flags);

  transpose2_kernel<<<dim3(HID / 64, HID / 64, 16), 256, 0, stream>>>(W1, W2, w1t, w2t, flags);

  logits_kernel<<<dim3(T_TOK / 4), 256, 0, stream>>>(x, Wr, br, kptr, flags, tokmap, xbf);
  bin1_kernel<<<dim3(NBINB), 128, 0, stream>>>(tokmap, kptr, bhist);
  scan_kernel<<<dim3(1), 256, 0, stream>>>(bhist, counts, offsets);
  bin2_kernel<<<dim3(NBINB), 128, 0, stream>>>(bhist, offsets, kptr, tok_list, tokmap);

  gemm1_kernel<<<dim3(8 * 16 * 12), 256, 0, stream>>>(
      xbf, w1t, b1, counts, offsets, tok_list, flags, hbuf);
  gemm2_kernel<<<dim3(8 * 16 * 8), 256, 0, stream>>>(
      hbuf, w2t, b2, counts, offsets, flags, ybuf);

  combine_kernel<<<dim3(T_TOK / 4), 256, 0, stream>>>(ybuf, tokmap, kptr, flags, d_out);
}

// Round 8
// 368.508 us; speedup vs baseline: 1.1967x; 1.0884x over previous
//
#include <hip/hip_runtime.h>
#include <hip/hip_bf16.h>
#include <math.h>

#define T_TOK 8192
#define EMB   1024
#define HID   1536
#define NE    8
#define NBINB 64
#define BINTOK (T_TOK / NBINB)

typedef float  floatx4 __attribute__((ext_vector_type(4)));
typedef __bf16 bf16x8  __attribute__((ext_vector_type(8)));

// ---- workspace layout (bytes) ----
#define WS_COUNTS   0
#define WS_OFFSETS  1024
#define WS_FLAGS    2048
#define WS_BHIST    4096
#define WS_TOKMAP   8192        // T*8*4
#define WS_TOKLIST  270336      // NE*T*4
#define WS_YBUF     532480      // ybuf 16384*1024*2; xbf aliases it (dead before gemm2 writes)
#define WS_W1T      34086912    // 25165824
#define WS_W2T      59252736    // 25165824
#define WS_H        84418560    // hbuf 16512 rows * 1536 * 2 (128-row pad for tail tiles)
#define WS_NEEDED   135143424

__device__ __forceinline__ float eload(const void* p, size_t idx, bool f32) {
  return f32 ? ((const float*)p)[idx] : (float)(((const __bf16*)p)[idx]);
}

// async global->LDS, 16B per lane; LDS dest = wave-uniform base + lane*16
__device__ __forceinline__ void glds16(const void* g, void* l) {
  __builtin_amdgcn_global_load_lds(
      (const __attribute__((address_space(1))) unsigned int*)g,
      (__attribute__((address_space(3))) unsigned int*)l, 16, 0, 0);
}

// ---------------- dtype sniff ----------------
__global__ __launch_bounds__(256)
void sniff_kernel(const void* p0, const void* p1, const void* p2, const void* p3,
                  const void* p4, const void* p5, const void* p6, int* flags) {
  const void* ps[7] = {p0, p1, p2, p3, p4, p5, p6};
  const int nelem[7] = {T_TOK * EMB, EMB * NE, NE, NE * EMB * HID, NE * HID, NE * HID * EMB, NE * EMB};
  int t = blockIdx.x;
  const unsigned* w = (const unsigned*)ps[t];
  int nw = nelem[t] / 2;
  if (nw > 2048) nw = 2048;
  __shared__ int s_pl, s_nz;
  if (threadIdx.x == 0) { s_pl = 0; s_nz = 0; }
  __syncthreads();
  int pl = 0, nz = 0;
  for (int i = threadIdx.x; i < nw; i += 256) {
    unsigned v = w[i];
    if (v == 0) continue;
    nz++;
    unsigned e = (v >> 23) & 0xFF;
    if (e >= 100 && e <= 150) pl++;
  }
  atomicAdd(&s_pl, pl);
  atomicAdd(&s_nz, nz);
  __syncthreads();
  if (threadIdx.x == 0) flags[t] = (2 * s_pl > s_nz) ? 1 : 0;
}

// ---------------- logits + top-k + x->bf16 conversion: one wave per token ----------------
__global__ __launch_bounds__(256)
void logits_kernel(const void* __restrict__ x, const void* __restrict__ Wr,
                   const void* __restrict__ br, const int* __restrict__ kptr,
                   const int* __restrict__ flags, int* __restrict__ topk,
                   __bf16* __restrict__ xbf) {
  const bool xf32  = flags[0] != 0;
  const bool wrf32 = flags[1] != 0;
  const bool brf32 = flags[2] != 0;
  const int wave = threadIdx.x >> 6;
  const int lane = threadIdx.x & 63;
  const int t = blockIdx.x * 4 + wave;

  float xv[16];
  {
    size_t base = (size_t)t * EMB + lane * 16;
    if (xf32) {
      const float* g = (const float*)x + base;
#pragma unroll
      for (int j = 0; j < 16; ++j) xv[j] = g[j];
    } else {
      bf16x8 u = *(const bf16x8*)((const __bf16*)x + base);
      bf16x8 v = *(const bf16x8*)((const __bf16*)x + base + 8);
#pragma unroll
      for (int j = 0; j < 8; ++j) { xv[j] = (float)u[j]; xv[8 + j] = (float)v[j]; }
    }
  }
  // write bf16 copy of x (uniform fast path for gemm1)
  {
    bf16x8 o0, o1;
#pragma unroll
    for (int j = 0; j < 8; ++j) { o0[j] = (__bf16)xv[j]; o1[j] = (__bf16)xv[8 + j]; }
    __bf16* xo = xbf + (size_t)t * EMB + lane * 16;
    *(bf16x8*)xo = o0;
    *(bf16x8*)(xo + 8) = o1;
  }
  float acc[NE];
#pragma unroll
  for (int e = 0; e < NE; ++e) acc[e] = 0.f;
  if (wrf32) {
#pragma unroll
    for (int j = 0; j < 16; ++j) {
      const float* wr = (const float*)Wr + (size_t)(lane * 16 + j) * NE;
#pragma unroll
      for (int e = 0; e < NE; ++e) acc[e] += xv[j] * wr[e];
    }
  } else {
#pragma unroll
    for (int j = 0; j < 16; ++j) {
      bf16x8 wr = *(const bf16x8*)((const __bf16*)Wr + (size_t)(lane * 16 + j) * NE);
#pragma unroll
      for (int e = 0; e < NE; ++e) acc[e] += xv[j] * (float)wr[e];
    }
  }
#pragma unroll
  for (int e = 0; e < NE; ++e) {
#pragma unroll
    for (int off = 32; off > 0; off >>= 1)
      acc[e] += __shfl_xor(acc[e], off, 64);
  }
  if (lane == 0) {
    int k = kptr[0];
    if (k < 1) k = 1; if (k > NE) k = NE;
    float lg[NE];
#pragma unroll
    for (int e = 0; e < NE; ++e) lg[e] = acc[e] + eload(br, e, brf32);
    for (int s = 0; s < k; ++s) {
      int bi = 0; float bv = lg[0];
#pragma unroll
      for (int e = 1; e < NE; ++e) { if (lg[e] > bv) { bv = lg[e]; bi = e; } }
      lg[bi] = -3.0e38f;
      topk[t * 8 + s] = bi;
    }
  }
}

// ---------------- binning: histogram -> scan -> place ----------------
__global__ __launch_bounds__(128)
void bin1_kernel(const int* __restrict__ topk, const int* __restrict__ kptr,
                 int* __restrict__ bhist) {
  __shared__ int lhist[NE];
  if (threadIdx.x < NE) lhist[threadIdx.x] = 0;
  __syncthreads();
  int k = kptr[0];
  if (k < 1) k = 1; if (k > NE) k = NE;
  const int t = blockIdx.x * BINTOK + threadIdx.x;
  for (int s = 0; s < k; ++s) atomicAdd(&lhist[topk[t * 8 + s] & 7], 1);
  __syncthreads();
  if (threadIdx.x < NE) bhist[blockIdx.x * NE + threadIdx.x] = lhist[threadIdx.x];
}

__global__ __launch_bounds__(256)
void scan_kernel(int* __restrict__ bhist, int* __restrict__ counts, int* __restrict__ offsets) {
  __shared__ int sh[NBINB * NE];
  __shared__ int scnt[NE];
  __shared__ int soff[NE + 1];
  const int tid = threadIdx.x;
  for (int i = tid; i < NBINB * NE; i += 256) sh[i] = bhist[i];
  __syncthreads();
  if (tid < NE) {
    int s = 0;
    for (int b = 0; b < NBINB; ++b) s += sh[b * NE + tid];
    scnt[tid] = s;
  }
  __syncthreads();
  if (tid == 0) {
    int s = 0;
    for (int e = 0; e < NE; ++e) { soff[e] = s; s += scnt[e]; }
    soff[NE] = s;
  }
  __syncthreads();
  if (tid < NE) {
    int run = soff[tid];
    for (int b = 0; b < NBINB; ++b) {
      int v = sh[b * NE + tid];
      sh[b * NE + tid] = run;
      run += v;
    }
  }
  __syncthreads();
  for (int i = tid; i < NBINB * NE; i += 256) bhist[i] = sh[i];
  if (tid < NE) counts[tid] = scnt[tid];
  if (tid < NE + 1) offsets[tid] = soff[tid];
}

__global__ __launch_bounds__(128)
void bin2_kernel(const int* __restrict__ bhist, const int* __restrict__ offsets,
                 const int* __restrict__ kptr,
                 int* __restrict__ tok_list, int* __restrict__ tokmap) {
  __shared__ int lbase[NE];
  __shared__ int lcnt[NE];
  if (threadIdx.x < NE) {
    lbase[threadIdx.x] = bhist[blockIdx.x * NE + threadIdx.x];
    lcnt[threadIdx.x] = 0;
  }
  __syncthreads();
  int k = kptr[0];
  if (k < 1) k = 1; if (k > NE) k = NE;
  const int t = blockIdx.x * BINTOK + threadIdx.x;
  for (int s = 0; s < k; ++s) {
    int e = tokmap[t * 8 + s] & 7;
    int pos = atomicAdd(&lcnt[e], 1);
    int grow = lbase[e] + pos;                   // compact global row
    tok_list[e * T_TOK + (grow - offsets[e])] = t;
    tokmap[t * 8 + s] = (e << 16) | grow;
  }
}

// ---------------- fused per-expert transposes (vectorized): W1 [E][H]->[H][E], W2 [H][E]->[E][H] ----------------
__global__ __launch_bounds__(256)
void transpose2_kernel(const void* __restrict__ W1, const void* __restrict__ W2,
                       __bf16* __restrict__ w1t, __bf16* __restrict__ w2t,
                       const int* __restrict__ flags) {
  const int z = blockIdx.z;             // 0..7 -> W1 expert z ; 8..15 -> W2 expert z-8
  const void* in; __bf16* out; int K, N; bool f32;
  if (z < 8) { in = W1; out = w1t; K = EMB; N = HID; f32 = flags[3] != 0; }
  else       { in = W2; out = w2t; K = HID; N = EMB; f32 = flags[5] != 0; }
  if ((int)blockIdx.x * 64 >= N || (int)blockIdx.y * 64 >= K) return;
  __shared__ __bf16 tile[64][66];       // +2 pad: write-phase column reads <=4-way conflict
  size_t eoff = (size_t)(z & 7) * (size_t)K * (size_t)N;
  const int n0 = blockIdx.x * 64;
  const int k0 = blockIdx.y * 64;
  const int tid = threadIdx.x;

  if (f32) {
    // 16B/lane reads: 16 threads/row x 4 floats, 16 rows/pass, 4 passes
    const int nn = (tid & 15) * 4;
    const int kr = tid >> 4;
#pragma unroll
    for (int p = 0; p < 4; ++p) {
      const int k = kr + p * 16;
      float4 v = *(const float4*)((const float*)in + eoff + (size_t)(k0 + k) * N + n0 + nn);
      tile[k][nn + 0] = (__bf16)v.x; tile[k][nn + 1] = (__bf16)v.y;
      tile[k][nn + 2] = (__bf16)v.z; tile[k][nn + 3] = (__bf16)v.w;
    }
  } else {
    // 16B/lane reads: 8 threads/row x 8 bf16, 32 rows/pass, 2 passes
    const int nn = (tid & 7) * 8;
    const int kr = tid >> 3;
#pragma unroll
    for (int p = 0; p < 2; ++p) {
      const int k = kr + p * 32;
      bf16x8 v = *(const bf16x8*)((const __bf16*)in + eoff + (size_t)(k0 + k) * N + n0 + nn);
#pragma unroll
      for (int j = 0; j < 8; ++j) tile[k][nn + j] = v[j];
    }
  }
  __syncthreads();
  // 16B/lane writes: 8 threads/n-row x 8 k, 32 n-rows/pass, 2 passes
  const int kk = (tid & 7) * 8;
  const int nr = tid >> 3;
#pragma unroll
  for (int p = 0; p < 2; ++p) {
    const int n = nr + p * 32;
    bf16x8 o;
#pragma unroll
    for (int j = 0; j < 8; ++j) o[j] = tile[kk + j][n];
    *(bf16x8*)(out + eoff + (size_t)(n0 + n) * K + k0 + kk) = o;
  }
}

// =====================================================================
// m97-structure grouped GEMM, BK=64: 128x128 tile, 256 threads = 4 waves
// (2Mx2N, per-wave 64x64, acc[4][4]). 32KB LDS (As+Bs [128][64] bf16),
// 2 barriers per K-step; BK=64 halves the number of vmcnt(0) drain
// events vs BK=32 (gemm1 32->16, gemm2 48->24) at equal load volume.
// Staging: 8 glds16/thread/step; inst (wave,q) covers rows
// (q*4+wave)*8 + (lane>>3), chunk lane&7; swizzled source chunk
// cgs = (lane&7)^((lane>>3)&7)  (LDS[R][c] holds global chunk c^(R&7)).
// Fragment reads: chunk (s*4+fc)^(R&7) at row-stride 128B -> 2-way (free).
// M-tiles: strided persistent loop covers any expert count.
// =====================================================================

// ---------------- GEMM1: h = gelu(x_gather @ W1[e] + b1[e]) ----------------
__global__ __launch_bounds__(256, 4)
void gemm1_kernel(const __bf16* __restrict__ xbf, const __bf16* __restrict__ w1t,
                  const void* __restrict__ b1, const int* __restrict__ counts,
                  const int* __restrict__ offsets, const int* __restrict__ tok_list,
                  const int* __restrict__ flags, __bf16* __restrict__ hbuf) {
  const int flat = blockIdx.x;
  const int e   = flat & 7;              // expert -> XCD pin
  const int idx = flat >> 3;             // 0..191
  const int g   = idx / 12;              // 0..15 (mT stride group)
  const int nT  = idx % 12;              // 0..11
  const int cnt = counts[e];
  const bool b1f32 = flags[4] != 0;

  __shared__ __align__(16) __bf16 As[128 * 64];
  __shared__ __align__(16) __bf16 Bs[128 * 64];

  const int wave = threadIdx.x >> 6;
  const int lane = threadIdx.x & 63;
  const int lrow = lane >> 3;            // 0..7 (row within 8-row group)
  const int cgs  = (lane & 7) ^ lrow;    // swizzled source chunk (R&7 == lrow)

  int Rst[4];
#pragma unroll
  for (int q = 0; q < 4; ++q) Rst[q] = (q * 4 + wave) * 8 + lrow;   // 0..127, disjoint

  const __bf16* pB[4];
#pragma unroll
  for (int q = 0; q < 4; ++q)
    pB[q] = w1t + ((size_t)e * HID + nT * 128 + Rst[q]) * EMB + cgs * 8;

  const int wm = (wave & 1) * 64;
  const int wn = (wave >> 1) * 64;
  const int fr = lane & 15;
  const int fc = lane >> 4;              // 0..3
  int aOff0[4], aOff1[4], bOff0[4], bOff1[4];
#pragma unroll
  for (int i = 0; i < 4; ++i) {
    int R = wm + i * 16 + fr;
    aOff0[i] = R * 128 + (((fc)     ^ (R & 7)) << 4);
    aOff1[i] = R * 128 + (((fc + 4) ^ (R & 7)) << 4);
  }
#pragma unroll
  for (int j = 0; j < 4; ++j) {
    int R = wn + j * 16 + fr;
    bOff0[j] = R * 128 + (((fc)     ^ (R & 7)) << 4);
    bOff1[j] = R * 128 + (((fc + 4) ^ (R & 7)) << 4);
  }

  const int colBase = nT * 128 + wn + fr;
  float bv[4];
#pragma unroll
  for (int j = 0; j < 4; ++j) bv[j] = eload(b1, (size_t)e * HID + colBase + j * 16, b1f32);

  for (int mT = g; mT * 128 < cnt; mT += 16) {
    const __bf16* pA[4];
#pragma unroll
    for (int q = 0; q < 4; ++q) {
      const int tok = tok_list[e * T_TOK + mT * 128 + Rst[q]];  // pad entries = 0
      pA[q] = xbf + (size_t)tok * EMB + cgs * 8;
    }

    floatx4 acc[4][4];
#pragma unroll
    for (int i = 0; i < 4; ++i)
#pragma unroll
      for (int j = 0; j < 4; ++j) acc[i][j] = (floatx4){0.f, 0.f, 0.f, 0.f};

    for (int kb = 0; kb < EMB / 64; ++kb) {
      __syncthreads();                   // previous step's (and tile's) readers done
#pragma unroll
      for (int q = 0; q < 4; ++q) glds16(pA[q] + (size_t)kb * 64, As + (q * 4 + wave) * 512);
#pragma unroll
      for (int q = 0; q < 4; ++q) glds16(pB[q] + (size_t)kb * 64, Bs + (q * 4 + wave) * 512);
      __syncthreads();                   // vmcnt(0) drain -> LDS resident
      bf16x8 af[4], bfr[4];
#pragma unroll
      for (int i = 0; i < 4; ++i) af[i]  = *(const bf16x8*)((const char*)As + aOff0[i]);
#pragma unroll
      for (int j = 0; j < 4; ++j) bfr[j] = *(const bf16x8*)((const char*)Bs + bOff0[j]);
#pragma unroll
      for (int i = 0; i < 4; ++i)
#pragma unroll
        for (int j = 0; j < 4; ++j)
          acc[i][j] = __builtin_amdgcn_mfma_f32_16x16x32_bf16(af[i], bfr[j], acc[i][j], 0, 0, 0);
#pragma unroll
      for (int i = 0; i < 4; ++i) af[i]  = *(const bf16x8*)((const char*)As + aOff1[i]);
#pragma unroll
      for (int j = 0; j < 4; ++j) bfr[j] = *(const bf16x8*)((const char*)Bs + bOff1[j]);
#pragma unroll
      for (int i = 0; i < 4; ++i)
#pragma unroll
        for (int j = 0; j < 4; ++j)
          acc[i][j] = __builtin_amdgcn_mfma_f32_16x16x32_bf16(af[i], bfr[j], acc[i][j], 0, 0, 0);
    }

    const int hBase = offsets[e] + mT * 128;
#pragma unroll
    for (int i = 0; i < 4; ++i) {
      const int rowLoc = wm + i * 16 + fc * 4;
#pragma unroll
      for (int r = 0; r < 4; ++r) {
        const int row = rowLoc + r;
        if (mT * 128 + row < cnt) {
          __bf16* hp = hbuf + (size_t)(hBase + row) * HID + colBase;
#pragma unroll
          for (int j = 0; j < 4; ++j) {
            float v = acc[i][j][r] + bv[j];
            float gl = 0.5f * v * (1.0f + erff(v * 0.70710678118654752f));
            hp[j * 16] = (__bf16)gl;
          }
        }
      }
    }
  }
}

// ---------------- GEMM2: ybuf[row] = h @ W2[e] + b2[e] ----------------
__global__ __launch_bounds__(256, 4)
void gemm2_kernel(const __bf16* __restrict__ hbuf, const __bf16* __restrict__ w2t,
                  const void* __restrict__ b2, const int* __restrict__ counts,
                  const int* __restrict__ offsets, const int* __restrict__ flags,
                  __bf16* __restrict__ ybuf) {
  const int flat = blockIdx.x;
  const int e   = flat & 7;
  const int idx = flat >> 3;             // 0..127
  const int g   = idx >> 3;              // 0..15
  const int nT  = idx & 7;               // 0..7
  const int cnt = counts[e];
  const bool b2f32 = flags[6] != 0;

  __shared__ __align__(16) __bf16 As[128 * 64];
  __shared__ __align__(16) __bf16 Bs[128 * 64];

  const int wave = threadIdx.x >> 6;
  const int lane = threadIdx.x & 63;
  const int lrow = lane >> 3;
  const int cgs  = (lane & 7) ^ lrow;

  int Rst[4];
#pragma unroll
  for (int q = 0; q < 4; ++q) Rst[q] = (q * 4 + wave) * 8 + lrow;

  const __bf16* pB[4];
#pragma unroll
  for (int q = 0; q < 4; ++q)
    pB[q] = w2t + ((size_t)e * EMB + nT * 128 + Rst[q]) * HID + cgs * 8;

  const int wm = (wave & 1) * 64;
  const int wn = (wave >> 1) * 64;
  const int fr = lane & 15;
  const int fc = lane >> 4;
  int aOff0[4], aOff1[4], bOff0[4], bOff1[4];
#pragma unroll
  for (int i = 0; i < 4; ++i) {
    int R = wm + i * 16 + fr;
    aOff0[i] = R * 128 + (((fc)     ^ (R & 7)) << 4);
    aOff1[i] = R * 128 + (((fc + 4) ^ (R & 7)) << 4);
  }
#pragma unroll
  for (int j = 0; j < 4; ++j) {
    int R = wn + j * 16 + fr;
    bOff0[j] = R * 128 + (((fc)     ^ (R & 7)) << 4);
    bOff1[j] = R * 128 + (((fc + 4) ^ (R & 7)) << 4);
  }

  const int colBase = nT * 128 + wn + fr;
  float bv[4];
#pragma unroll
  for (int j = 0; j < 4; ++j) bv[j] = eload(b2, (size_t)e * EMB + colBase + j * 16, b2f32);

  for (int mT = g; mT * 128 < cnt; mT += 16) {
    const int rowBase = offsets[e] + mT * 128;
    // overhang rows read next expert's rows / 128-row hbuf pad (<16512): discarded per-row below
    const __bf16* pA[4];
#pragma unroll
    for (int q = 0; q < 4; ++q)
      pA[q] = hbuf + (size_t)(rowBase + Rst[q]) * HID + cgs * 8;

    floatx4 acc[4][4];
#pragma unroll
    for (int i = 0; i < 4; ++i)
#pragma unroll
      for (int j = 0; j < 4; ++j) acc[i][j] = (floatx4){0.f, 0.f, 0.f, 0.f};

    for (int kb = 0; kb < HID / 64; ++kb) {
      __syncthreads();
#pragma unroll
      for (int q = 0; q < 4; ++q) glds16(pA[q] + (size_t)kb * 64, As + (q * 4 + wave) * 512);
#pragma unroll
      for (int q = 0; q < 4; ++q) glds16(pB[q] + (size_t)kb * 64, Bs + (q * 4 + wave) * 512);
      __syncthreads();
      bf16x8 af[4], bfr[4];
#pragma unroll
      for (int i = 0; i < 4; ++i) af[i]  = *(const bf16x8*)((const char*)As + aOff0[i]);
#pragma unroll
      for (int j = 0; j < 4; ++j) bfr[j] = *(const bf16x8*)((const char*)Bs + bOff0[j]);
#pragma unroll
      for (int i = 0; i < 4; ++i)
#pragma unroll
        for (int j = 0; j < 4; ++j)
          acc[i][j] = __builtin_amdgcn_mfma_f32_16x16x32_bf16(af[i], bfr[j], acc[i][j], 0, 0, 0);
#pragma unroll
      for (int i = 0; i < 4; ++i) af[i]  = *(const bf16x8*)((const char*)As + aOff1[i]);
#pragma unroll
      for (int j = 0; j < 4; ++j) bfr[j] = *(const bf16x8*)((const char*)Bs + bOff1[j]);
#pragma unroll
      for (int i = 0; i < 4; ++i)
#pragma unroll
        for (int j = 0; j < 4; ++j)
          acc[i][j] = __builtin_amdgcn_mfma_f32_16x16x32_bf16(af[i], bfr[j], acc[i][j], 0, 0, 0);
    }

#pragma unroll
    for (int i = 0; i < 4; ++i) {
      const int rowLoc = wm + i * 16 + fc * 4;
#pragma unroll
      for (int r = 0; r < 4; ++r) {
        const int row = rowLoc + r;
        if (mT * 128 + row < cnt) {
          __bf16* yp = ybuf + (size_t)(rowBase + row) * EMB + colBase;
#pragma unroll
          for (int j = 0; j < 4; ++j)
            yp[j * 16] = (__bf16)(acc[i][j][r] + bv[j]);
        }
      }
    }
  }
}

// ---------------- combine: out[t] = (sum_s ybuf[row(t,s)]) / k ----------------
__global__ __launch_bounds__(256)
void combine_kernel(const __bf16* __restrict__ ybuf, const int* __restrict__ tokmap,
                    const int* __restrict__ kptr, const int* __restrict__ flags,
                    void* __restrict__ out) {
  const bool f32 = flags[0] != 0;
  const int wave = threadIdx.x >> 6;
  const int lane = threadIdx.x & 63;
  const int t = blockIdx.x * 4 + wave;
  int k = kptr[0];
  if (k < 1) k = 1; if (k > NE) k = NE;
  const float invk = 1.0f / (float)k;
  int rows[NE];
  for (int s = 0; s < k; ++s) rows[s] = tokmap[t * 8 + s] & 0xFFFF;
#pragma unroll
  for (int c = 0; c < 2; ++c) {
    const int i = c * 512 + lane * 8;
    float a[8];
#pragma unroll
    for (int j = 0; j < 8; ++j) a[j] = 0.f;
    for (int s = 0; s < k; ++s) {
      bf16x8 y = *(const bf16x8*)(ybuf + (size_t)rows[s] * EMB + i);
#pragma unroll
      for (int j = 0; j < 8; ++j) a[j] += (float)y[j];
    }
    if (f32) {
      float* op = (float*)out + (size_t)t * EMB + i;
      float4 u = {a[0] * invk, a[1] * invk, a[2] * invk, a[3] * invk};
      float4 v = {a[4] * invk, a[5] * invk, a[6] * invk, a[7] * invk};
      *(float4*)op = u;
      *(float4*)(op + 4) = v;
    } else {
      bf16x8 o;
#pragma unroll
      for (int j = 0; j < 8; ++j) o[j] = (__bf16)(a[j] * invk);
      *(bf16x8*)((__bf16*)out + (size_t)t * EMB + i) = o;
    }
  }
}

extern "C" void kernel_launch(void* const* d_in, const int* in_sizes, int n_in,
                              void* d_out, int out_size, void* d_ws, size_t ws_size,
                              hipStream_t stream) {
  (void)in_sizes; (void)n_in; (void)out_size;
  if (ws_size < (size_t)WS_NEEDED) return;

  const void* x  = d_in[0];
  const void* Wr = d_in[1];
  const void* br = d_in[2];
  const void* W1 = d_in[3];
  const void* b1 = d_in[4];
  const void* W2 = d_in[5];
  const void* b2 = d_in[6];
  const int* kptr = (const int*)d_in[7];

  char* ws = (char*)d_ws;
  int*    counts   = (int*)(ws + WS_COUNTS);
  int*    offsets  = (int*)(ws + WS_OFFSETS);
  int*    flags    = (int*)(ws + WS_FLAGS);
  int*    bhist    = (int*)(ws + WS_BHIST);
  int*    tokmap   = (int*)(ws + WS_TOKMAP);
  int*    tok_list = (int*)(ws + WS_TOKLIST);
  __bf16* ybuf     = (__bf16*)(ws + WS_YBUF);
  __bf16* xbf      = (__bf16*)(ws + WS_YBUF);   // aliases ybuf; dead before gemm2 writes
  __bf16* w1t      = (__bf16*)(ws + WS_W1T);
  __bf16* w2t      = (__bf16*)(ws + WS_W2T);
  __bf16* hbuf     = (__bf16*)(ws + WS_H);

  // only the tok_list pad must be deterministic (gemm1 tail tiles read it)
  hipMemsetAsync(ws + WS_TOKLIST, 0, NE * T_TOK * 4, stream);

  sniff_kernel<<<dim3(7), 256, 0, stream>>>(x, Wr, br, W1, b1, W2, b2, flags);

  transpose2_kernel<<<dim3(HID / 64, HID / 64, 16), 256, 0, stream>>>(W1, W2, w1t, w2t, flags);

  logits_kernel<<<dim3(T_TOK / 4), 256, 0, stream>>>(x, Wr, br, kptr, flags, tokmap, xbf);
  bin1_kernel<<<dim3(NBINB), 128, 0, stream>>>(tokmap, kptr, bhist);
  scan_kernel<<<dim3(1), 256, 0, stream>>>(bhist, counts, offsets);
  bin2_kernel<<<dim3(NBINB), 128, 0, stream>>>(bhist, offsets, kptr, tok_list, tokmap);

  gemm1_kernel<<<dim3(8 * 16 * 12), 256, 0, stream>>>(
      xbf, w1t, b1, counts, offsets, tok_list, flags, hbuf);
  gemm2_kernel<<<dim3(8 * 16 * 8), 256, 0, stream>>>(
      hbuf, w2t, b2, counts, offsets, flags, ybuf);

  combine_kernel<<<dim3(T_TOK / 4), 256, 0, stream>>>(ybuf, tokmap, kptr, flags, d_out);
}